// Round 5
// baseline (1479.099 us; speedup 1.0000x reference)
//
#include <hip/hip_runtime.h>
#include <hip/hip_cooperative_groups.h>

namespace cg = cooperative_groups;

#define NN 262144
#define RANK 16
#define NNZ_K 1310720
#define NCH 2048         // chunks of 128 elems
#define GRID 1024        // 4 blocks/CU on 256 CUs -> co-resident

struct P8 { const float* p[8]; };

// ---------------------------------------------------------------------------
// Single cooperative kernel: all phases separated by grid.sync().
// Phase bodies are verbatim from the previously-measured kernels.
// ---------------------------------------------------------------------------
__global__ __launch_bounds__(256, 4) void k_all(const float* __restrict__ leaf,
                                                P8 u, P8 v,
                                                const int* __restrict__ idx,
                                                const float* __restrict__ vals,
                                                const float* __restrict__ z,
                                                float* __restrict__ part,
                                                float* __restrict__ tg,
                                                float* __restrict__ loss,
                                                float* __restrict__ w,
                                                float* __restrict__ y,
                                                float* __restrict__ out) {
    cg::grid_group grid = cg::this_grid();
    const int tid = threadIdx.x;
    const int bid = blockIdx.x;

    __shared__ float red[8][4][16];   // P1
    __shared__ float red2[256];       // P2
    __shared__ float wl[128];         // P3
    __shared__ float pb[128];
    __shared__ float tl[8][16];
    __shared__ float rl[4];           // P5

    // ---- P0: zero y (1 elem/thread, exact cover) and loss ----
    y[bid * 256 + tid] = 0.f;
    if (bid == 0 && tid == 0) loss[0] = 0.f;

    // ---- P1: levels partials  part[l][ch][r] ----
    {
        const int q    = tid & 3;
        const int e    = tid >> 2;        // 0..63
        const int lane = tid & 63;
        const int wv   = tid >> 6;        // 0..3

        for (int ch = bid; ch < NCH; ch += GRID) {
            const int base = ch * 128;
#pragma unroll
            for (int g = 0; g < 2; ++g) {
                float4 acc[4];
#pragma unroll
                for (int l = 0; l < 4; ++l) acc[l] = make_float4(0.f, 0.f, 0.f, 0.f);
#pragma unroll
                for (int it = 0; it < 2; ++it) {
                    const int jl = it * 64 + e;
                    const size_t j = (size_t)(base + jl);
                    const float zz = z[j];
                    float4 vv[4];
#pragma unroll
                    for (int l = 0; l < 4; ++l)
                        vv[l] = *(const float4*)(v.p[g * 4 + l] + j * RANK + q * 4);
#pragma unroll
                    for (int l = 0; l < 4; ++l) {
                        acc[l].x += vv[l].x * zz;
                        acc[l].y += vv[l].y * zz;
                        acc[l].z += vv[l].z * zz;
                        acc[l].w += vv[l].w * zz;
                    }
                }
#pragma unroll
                for (int l = 0; l < 4; ++l) {
                    float4 a = acc[l];
#pragma unroll
                    for (int m = 4; m <= 32; m <<= 1) {
                        a.x += __shfl_xor(a.x, m);
                        a.y += __shfl_xor(a.y, m);
                        a.z += __shfl_xor(a.z, m);
                        a.w += __shfl_xor(a.w, m);
                    }
                    if (lane < 4) *(float4*)&red[g * 4 + l][wv][lane * 4] = a;
                }
            }
            __syncthreads();
            if (tid < 128) {
                const int l = tid >> 4;
                const int r = tid & 15;
                const float s = red[l][0][r] + red[l][1][r] + red[l][2][r] + red[l][3][r];
                part[(l * NCH + ch) * 16 + r] = s;
            }
            __syncthreads();   // WAR on red before next chunk
        }
    }
    __threadfence();
    grid.sync();

    // ---- P2: tree-reduce part -> tg (510 tasks on first 510 blocks) ----
    if (bid < 510) {
        const int t = bid + 2;
        const int l = 30 - __clz(t);
        const int h = t - (2 << l);
        const int cnt = 1024 >> l;
        const int c0  = h * cnt;
        const int r = tid & 15;
        const int g = tid >> 4;

        float s = 0.f;
        for (int c = c0 + g; c < c0 + cnt; c += 16)
            s += part[(l * NCH + c) * 16 + r];

        red2[tid] = s;
        __syncthreads();
        if (tid < 16) {
            float ss = 0.f;
#pragma unroll
            for (int k = 0; k < 16; ++k) ss += red2[k * 16 + r];
            tg[((2 << l) - 2 + h) * 16 + r] = ss;
        }
    }
    __threadfence();
    grid.sync();

    // ---- P3: w = leaf part + u-accumulation ----
    for (int ch = bid; ch < NCH; ch += GRID) {
        const int base = ch * 128;

        if (tid < 128) {
            const int l = tid >> 4;
            const int r = tid & 15;
            const int h = base >> (17 - l);
            tl[l][r] = tg[(((2 << l) - 2) + (h ^ 1)) * 16 + r];
        }

        // Phase A: leaf blocks, one wave each
        {
            const int l6 = tid & 63;
            const int wv = tid >> 6;
            const int b  = ch * 4 + wv;
            const int r  = l6 >> 1;

            const float* Lb = leaf + (size_t)b * 1024 + r * 32 + (l6 & 1) * 16;
            const float4 L0 = ((const float4*)Lb)[0];
            const float4 L1 = ((const float4*)Lb)[1];
            const float4 L2 = ((const float4*)Lb)[2];
            const float4 L3 = ((const float4*)Lb)[3];

            const float zl = z[b * 32 + (l6 & 31)];
            const float xr = __shfl(zl, r);

            float4 t0 = make_float4(L0.x * xr, L0.y * xr, L0.z * xr, L0.w * xr);
            float4 t1 = make_float4(L1.x * xr, L1.y * xr, L1.z * xr, L1.w * xr);
            float4 t2 = make_float4(L2.x * xr, L2.y * xr, L2.z * xr, L2.w * xr);
            float4 t3 = make_float4(L3.x * xr, L3.y * xr, L3.z * xr, L3.w * xr);

#pragma unroll
            for (int m = 2; m <= 32; m <<= 1) {
                t0.x += __shfl_xor(t0.x, m); t0.y += __shfl_xor(t0.y, m);
                t0.z += __shfl_xor(t0.z, m); t0.w += __shfl_xor(t0.w, m);
                t1.x += __shfl_xor(t1.x, m); t1.y += __shfl_xor(t1.y, m);
                t1.z += __shfl_xor(t1.z, m); t1.w += __shfl_xor(t1.w, m);
                t2.x += __shfl_xor(t2.x, m); t2.y += __shfl_xor(t2.y, m);
                t2.z += __shfl_xor(t2.z, m); t2.w += __shfl_xor(t2.w, m);
                t3.x += __shfl_xor(t3.x, m); t3.y += __shfl_xor(t3.y, m);
                t3.z += __shfl_xor(t3.z, m); t3.w += __shfl_xor(t3.w, m);
            }

            float yp = L0.x * t0.x + L0.y * t0.y + L0.z * t0.z + L0.w * t0.w
                     + L1.x * t1.x + L1.y * t1.y + L1.z * t1.z + L1.w * t1.w
                     + L2.x * t2.x + L2.y * t2.y + L2.z * t2.z + L2.w * t2.w
                     + L3.x * t3.x + L3.y * t3.y + L3.z * t3.z + L3.w * t3.w;
            yp += __shfl_xor(yp, 1);

            const float w0  = yp + 1e-4f * xr;
            const float o   = __shfl(w0, (l6 & 31) * 2);
            if (l6 < 32) wl[wv * 32 + l6] = o;
        }
        __syncthreads();

        // Phase B: 2 threads per element, 4 levels each
        {
            const int half = tid >> 7;
            const int e    = tid & 127;
            const size_t i = (size_t)(base + e);
            const int l0   = half * 4;

            float accs[4];
#pragma unroll
            for (int lp = 0; lp < 2; ++lp) {
                const int l = l0 + lp * 2;
                float4 a[8];
                {
                    const float4* up0 = (const float4*)(u.p[l] + i * RANK);
                    const float4* up1 = (const float4*)(u.p[l + 1] + i * RANK);
#pragma unroll
                    for (int k = 0; k < 4; ++k) a[k]     = up0[k];
#pragma unroll
                    for (int k = 0; k < 4; ++k) a[4 + k] = up1[k];
                }
#pragma unroll
                for (int s = 0; s < 2; ++s) {
                    const float4 t0 = *(const float4*)&tl[l + s][0];
                    const float4 t1 = *(const float4*)&tl[l + s][4];
                    const float4 t2 = *(const float4*)&tl[l + s][8];
                    const float4 t3 = *(const float4*)&tl[l + s][12];
                    const float4* av = &a[s * 4];
                    accs[lp * 2 + s] = av[0].x * t0.x + av[0].y * t0.y + av[0].z * t0.z + av[0].w * t0.w
                                     + av[1].x * t1.x + av[1].y * t1.y + av[1].z * t1.z + av[1].w * t1.w
                                     + av[2].x * t2.x + av[2].y * t2.y + av[2].z * t2.z + av[2].w * t2.w
                                     + av[3].x * t3.x + av[3].y * t3.y + av[3].z * t3.z + av[3].w * t3.w;
                }
            }
            const float sum = (accs[0] + accs[1]) + (accs[2] + accs[3]);
            if (half) pb[e] = sum;
            __syncthreads();
            if (!half) w[i] = wl[e] + sum + pb[e];
        }
        __syncthreads();   // WAR on wl/pb/tl before next chunk
    }
    __threadfence();
    grid.sync();

    // ---- P4: SpMV via direct atomics into y ----
    {
        const int id = bid * 256 + tid;
        for (int k = id * 4; k < NNZ_K; k += GRID * 256 * 4) {
            const int4   r4 = *(const int4*)(idx + k);
            const int4   c4 = *(const int4*)(idx + NNZ_K + k);
            const float4 v4 = *(const float4*)(vals + k);
            atomicAdd(&y[r4.x], v4.x * w[c4.x]);
            atomicAdd(&y[r4.y], v4.y * w[c4.y]);
            atomicAdd(&y[r4.z], v4.z * w[c4.z]);
            atomicAdd(&y[r4.w], v4.w * w[c4.w]);
        }
    }
    __threadfence();
    grid.sync();

    // ---- P5: loss = sum((y - z)^2), 1 elem/thread ----
    {
        const int id = bid * 256 + tid;
        const float d = y[id] - z[id];
        float s = d * d;
#pragma unroll
        for (int m = 32; m >= 1; m >>= 1) s += __shfl_down(s, m);
        if ((tid & 63) == 0) rl[tid >> 6] = s;
        __syncthreads();
        if (tid == 0) atomicAdd(loss, rl[0] + rl[1] + rl[2] + rl[3]);
    }
    __threadfence();
    grid.sync();

    // ---- P6: finalize ----
    if (bid == 0 && tid == 0) out[0] = loss[0] * (1.0f / (float)NN);
}

// ======================= fallback multi-kernel path ========================
__global__ __launch_bounds__(256, 6) void k_levels_t(P8 v, const float* __restrict__ z,
                                                     float* __restrict__ part) {
    __shared__ float red[8][4][16];
    const int tid  = threadIdx.x;
    const int base = blockIdx.x * 128;
    const int q    = tid & 3;
    const int e    = tid >> 2;
    const int lane = tid & 63;
    const int wv   = tid >> 6;

#pragma unroll
    for (int g = 0; g < 2; ++g) {
        float4 acc[4];
#pragma unroll
        for (int l = 0; l < 4; ++l) acc[l] = make_float4(0.f, 0.f, 0.f, 0.f);
#pragma unroll
        for (int it = 0; it < 2; ++it) {
            const int jl = it * 64 + e;
            const size_t j = (size_t)(base + jl);
            const float zz = z[j];
            float4 vv[4];
#pragma unroll
            for (int l = 0; l < 4; ++l)
                vv[l] = *(const float4*)(v.p[g * 4 + l] + j * RANK + q * 4);
#pragma unroll
            for (int l = 0; l < 4; ++l) {
                acc[l].x += vv[l].x * zz;
                acc[l].y += vv[l].y * zz;
                acc[l].z += vv[l].z * zz;
                acc[l].w += vv[l].w * zz;
            }
        }
#pragma unroll
        for (int l = 0; l < 4; ++l) {
            float4 a = acc[l];
#pragma unroll
            for (int m = 4; m <= 32; m <<= 1) {
                a.x += __shfl_xor(a.x, m);
                a.y += __shfl_xor(a.y, m);
                a.z += __shfl_xor(a.z, m);
                a.w += __shfl_xor(a.w, m);
            }
            if (lane < 4) *(float4*)&red[g * 4 + l][wv][lane * 4] = a;
        }
    }
    __syncthreads();

    if (tid < 128) {
        const int l = tid >> 4;
        const int r = tid & 15;
        const float s = red[l][0][r] + red[l][1][r] + red[l][2][r] + red[l][3][r];
        part[(l * NCH + blockIdx.x) * 16 + r] = s;
    }
}

__global__ __launch_bounds__(256) void k_reduce_t(const float* __restrict__ part,
                                                  float* __restrict__ tg,
                                                  float* __restrict__ loss) {
    const int b = blockIdx.x;
    if (b == 0 && threadIdx.x == 0) loss[0] = 0.f;
    const int t = b + 2;
    const int l = 30 - __clz(t);
    const int h = t - (2 << l);
    const int cnt = 1024 >> l;
    const int c0  = h * cnt;
    const int r = threadIdx.x & 15;
    const int g = threadIdx.x >> 4;

    float s = 0.f;
    for (int c = c0 + g; c < c0 + cnt; c += 16)
        s += part[(l * NCH + c) * 16 + r];

    __shared__ float red[256];
    red[threadIdx.x] = s;
    __syncthreads();
    if (threadIdx.x < 16) {
        float ss = 0.f;
#pragma unroll
        for (int k = 0; k < 16; ++k) ss += red[k * 16 + r];
        tg[((2 << l) - 2 + h) * 16 + r] = ss;
    }
}

__global__ __launch_bounds__(256, 6) void k_w(const float* __restrict__ leaf, P8 u,
                                              const float* __restrict__ z,
                                              const float* __restrict__ tg,
                                              float* __restrict__ w,
                                              float* __restrict__ y) {
    __shared__ float wl[128];
    __shared__ float pb[128];
    __shared__ float tl[8][16];

    const int tid  = threadIdx.x;
    const int base = blockIdx.x * 128;

    if (tid < 128) {
        const int l = tid >> 4;
        const int r = tid & 15;
        const int h = base >> (17 - l);
        tl[l][r] = tg[(((2 << l) - 2) + (h ^ 1)) * 16 + r];
    }

    {
        const int l6 = tid & 63;
        const int wv = tid >> 6;
        const int b  = blockIdx.x * 4 + wv;
        const int r  = l6 >> 1;

        const float* Lb = leaf + (size_t)b * 1024 + r * 32 + (l6 & 1) * 16;
        const float4 L0 = ((const float4*)Lb)[0];
        const float4 L1 = ((const float4*)Lb)[1];
        const float4 L2 = ((const float4*)Lb)[2];
        const float4 L3 = ((const float4*)Lb)[3];

        const float zl = z[b * 32 + (l6 & 31)];
        const float xr = __shfl(zl, r);

        float4 t0 = make_float4(L0.x * xr, L0.y * xr, L0.z * xr, L0.w * xr);
        float4 t1 = make_float4(L1.x * xr, L1.y * xr, L1.z * xr, L1.w * xr);
        float4 t2 = make_float4(L2.x * xr, L2.y * xr, L2.z * xr, L2.w * xr);
        float4 t3 = make_float4(L3.x * xr, L3.y * xr, L3.z * xr, L3.w * xr);

#pragma unroll
        for (int m = 2; m <= 32; m <<= 1) {
            t0.x += __shfl_xor(t0.x, m); t0.y += __shfl_xor(t0.y, m);
            t0.z += __shfl_xor(t0.z, m); t0.w += __shfl_xor(t0.w, m);
            t1.x += __shfl_xor(t1.x, m); t1.y += __shfl_xor(t1.y, m);
            t1.z += __shfl_xor(t1.z, m); t1.w += __shfl_xor(t1.w, m);
            t2.x += __shfl_xor(t2.x, m); t2.y += __shfl_xor(t2.y, m);
            t2.z += __shfl_xor(t2.z, m); t2.w += __shfl_xor(t2.w, m);
            t3.x += __shfl_xor(t3.x, m); t3.y += __shfl_xor(t3.y, m);
            t3.z += __shfl_xor(t3.z, m); t3.w += __shfl_xor(t3.w, m);
        }

        float yp = L0.x * t0.x + L0.y * t0.y + L0.z * t0.z + L0.w * t0.w
                 + L1.x * t1.x + L1.y * t1.y + L1.z * t1.z + L1.w * t1.w
                 + L2.x * t2.x + L2.y * t2.y + L2.z * t2.z + L2.w * t2.w
                 + L3.x * t3.x + L3.y * t3.y + L3.z * t3.z + L3.w * t3.w;
        yp += __shfl_xor(yp, 1);

        const float w0  = yp + 1e-4f * xr;
        const float out = __shfl(w0, (l6 & 31) * 2);
        if (l6 < 32) wl[wv * 32 + l6] = out;
    }
    __syncthreads();

    const int half = tid >> 7;
    const int e    = tid & 127;
    const size_t i = (size_t)(base + e);
    const int l0   = half * 4;

    float accs[4];
#pragma unroll
    for (int lp = 0; lp < 2; ++lp) {
        const int l = l0 + lp * 2;
        float4 a[8];
        {
            const float4* up0 = (const float4*)(u.p[l] + i * RANK);
            const float4* up1 = (const float4*)(u.p[l + 1] + i * RANK);
#pragma unroll
            for (int k = 0; k < 4; ++k) a[k]     = up0[k];
#pragma unroll
            for (int k = 0; k < 4; ++k) a[4 + k] = up1[k];
        }
#pragma unroll
        for (int s = 0; s < 2; ++s) {
            const float4 t0 = *(const float4*)&tl[l + s][0];
            const float4 t1 = *(const float4*)&tl[l + s][4];
            const float4 t2 = *(const float4*)&tl[l + s][8];
            const float4 t3 = *(const float4*)&tl[l + s][12];
            const float4* av = &a[s * 4];
            accs[lp * 2 + s] = av[0].x * t0.x + av[0].y * t0.y + av[0].z * t0.z + av[0].w * t0.w
                             + av[1].x * t1.x + av[1].y * t1.y + av[1].z * t1.z + av[1].w * t1.w
                             + av[2].x * t2.x + av[2].y * t2.y + av[2].z * t2.z + av[2].w * t2.w
                             + av[3].x * t3.x + av[3].y * t3.y + av[3].z * t3.z + av[3].w * t3.w;
        }
    }
    const float sum = (accs[0] + accs[1]) + (accs[2] + accs[3]);
    if (half) pb[e] = sum;
    __syncthreads();
    if (!half) {
        w[i] = wl[e] + sum + pb[e];
        y[i] = 0.f;
    }
}

__global__ __launch_bounds__(256) void k_spmv(const int* __restrict__ idx,
                                              const float* __restrict__ vals,
                                              const float* __restrict__ w,
                                              float* __restrict__ y) {
    const int k = (blockIdx.x * 256 + threadIdx.x) * 4;
    const int4   r4 = *(const int4*)(idx + k);
    const int4   c4 = *(const int4*)(idx + NNZ_K + k);
    const float4 v4 = *(const float4*)(vals + k);
    atomicAdd(&y[r4.x], v4.x * w[c4.x]);
    atomicAdd(&y[r4.y], v4.y * w[c4.y]);
    atomicAdd(&y[r4.z], v4.z * w[c4.z]);
    atomicAdd(&y[r4.w], v4.w * w[c4.w]);
}

__global__ __launch_bounds__(256) void k_loss(const float* __restrict__ y,
                                              const float* __restrict__ z,
                                              float* __restrict__ loss) {
    const int i = blockIdx.x * 256 + threadIdx.x;
    const float4 a = ((const float4*)y)[i];
    const float4 b = ((const float4*)z)[i];
    const float dx = a.x - b.x, dy = a.y - b.y, dz = a.z - b.z, dw = a.w - b.w;
    float s = dx * dx + dy * dy + dz * dz + dw * dw;
#pragma unroll
    for (int m = 32; m >= 1; m >>= 1) s += __shfl_down(s, m);
    __shared__ float r4s[4];
    const int lane = threadIdx.x & 63, wv = threadIdx.x >> 6;
    if (lane == 0) r4s[wv] = s;
    __syncthreads();
    if (threadIdx.x == 0) atomicAdd(loss, r4s[0] + r4s[1] + r4s[2] + r4s[3]);
}

__global__ void k_fin(const float* __restrict__ loss, float* __restrict__ out) {
    out[0] = loss[0] * (1.0f / (float)NN);
}

// ---------------------------------------------------------------------------
extern "C" void kernel_launch(void* const* d_in, const int* in_sizes, int n_in,
                              void* d_out, int out_size, void* d_ws, size_t ws_size,
                              hipStream_t stream) {
    const float* leaf = (const float*)d_in[0];
    P8 u, v;
    for (int l = 0; l < 8; ++l) {
        u.p[l] = (const float*)d_in[1 + 2 * l];
        v.p[l] = (const float*)d_in[2 + 2 * l];
    }
    const int*   Aidx  = (const int*)d_in[17];
    const float* Avals = (const float*)d_in[18];
    const float* z     = (const float*)d_in[19];

    float* ws   = (float*)d_ws;
    // layout (floats):
    float* part = ws;                      // 8*NCH*16 = 262144
    float* tg   = ws + 262144;             // 8192
    float* loss = ws + 270336;             // 1 (pad to 270400)
    float* w    = ws + 270400;             // 262144 -> 532544
    float* y    = ws + 532544;             // 262144 -> 794688 (~3.03 MB)
    float* outp = (float*)d_out;

    void* args[] = { (void*)&leaf, (void*)&u, (void*)&v, (void*)&Aidx,
                     (void*)&Avals, (void*)&z, (void*)&part, (void*)&tg,
                     (void*)&loss, (void*)&w, (void*)&y, (void*)&outp };

    hipError_t err = hipLaunchCooperativeKernel((const void*)k_all, dim3(GRID),
                                                dim3(256), args, 0, stream);
    if (err != hipSuccess) {
        // fallback: previous multi-kernel sequence
        k_levels_t<<<NCH, 256, 0, stream>>>(v, z, part);
        k_reduce_t<<<510, 256, 0, stream>>>(part, tg, loss);
        k_w       <<<NN / 128, 256, 0, stream>>>(leaf, u, z, tg, w, y);
        k_spmv    <<<NNZ_K / 1024, 256, 0, stream>>>(Aidx, Avals, w, y);
        k_loss    <<<NN / 1024, 256, 0, stream>>>(y, z, loss);
        k_fin     <<<1, 1, 0, stream>>>(loss, outp);
    }
}

// Round 6
// 349.817 us; speedup vs baseline: 4.2282x; 4.2282x over previous
//
#include <hip/hip_runtime.h>

#define NN 262144
#define RANK 16
#define NNZ_K 1310720
#define NB 512           // k_bin blocks
#define BPB 2560         // nnz per k_bin block
#define NBKT 256         // row buckets (1024 rows each)
#define RPB 1024         // rows per bucket
#define SPAN 256         // elems per vt/uacc block
#define NSP 1024         // NN / SPAN

struct P8 { const float* p[8]; };

// ---------------------------------------------------------------------------
// K1 "front": fused independent work.
//   bid <  NSP  : v-levels partials, ONE ARRAY AT A TIME (level-sequential)
//   bid >= NSP  : leaf matvec w0 = L(L^T x) + 1e-4 x  (wave per 32x32 block)
// Level-sequential streaming = chip-wide single-stream passes (tests the
// 8-interleaved-streams channel-conflict theory).
// ---------------------------------------------------------------------------
__global__ __launch_bounds__(256, 4) void k_front(const float* __restrict__ leaf,
                                                  P8 v,
                                                  const float* __restrict__ z,
                                                  float* __restrict__ part,
                                                  float* __restrict__ w) {
    const int tid = threadIdx.x;

    if (blockIdx.x < NSP) {
        // ---------------- v-levels partials ----------------
        __shared__ float red[8][4][16];
        const int cb   = blockIdx.x;
        const int base = cb * SPAN;
        const int q    = tid & 3;
        const int e    = tid >> 2;        // 0..63
        const int lane = tid & 63;
        const int wv   = tid >> 6;        // 0..3

        const float z0 = z[base + e];
        const float z1 = z[base + 64 + e];
        const float z2 = z[base + 128 + e];
        const float z3 = z[base + 192 + e];

#pragma unroll
        for (int l = 0; l < 8; ++l) {
            const float* vp = v.p[l];
            const float4 a0 = *(const float4*)(vp + (size_t)(base + e) * RANK + q * 4);
            const float4 a1 = *(const float4*)(vp + (size_t)(base + 64 + e) * RANK + q * 4);
            const float4 a2 = *(const float4*)(vp + (size_t)(base + 128 + e) * RANK + q * 4);
            const float4 a3 = *(const float4*)(vp + (size_t)(base + 192 + e) * RANK + q * 4);

            float4 acc;
            acc.x = a0.x * z0 + a1.x * z1 + a2.x * z2 + a3.x * z3;
            acc.y = a0.y * z0 + a1.y * z1 + a2.y * z2 + a3.y * z3;
            acc.z = a0.z * z0 + a1.z * z1 + a2.z * z2 + a3.z * z3;
            acc.w = a0.w * z0 + a1.w * z1 + a2.w * z2 + a3.w * z3;

#pragma unroll
            for (int m = 4; m <= 32; m <<= 1) {
                acc.x += __shfl_xor(acc.x, m);
                acc.y += __shfl_xor(acc.y, m);
                acc.z += __shfl_xor(acc.z, m);
                acc.w += __shfl_xor(acc.w, m);
            }
            if (lane < 4) *(float4*)&red[l][wv][lane * 4] = acc;
        }
        __syncthreads();

        if (tid < 128) {
            const int l = tid >> 4;
            const int r = tid & 15;
            const float s = red[l][0][r] + red[l][1][r] + red[l][2][r] + red[l][3][r];
            part[(l * NSP + cb) * 16 + r] = s;
        }
    } else {
        // ---------------- leaf matvec (verbatim-measured math) ----------------
        const int lb = blockIdx.x - NSP;
        const int l6 = tid & 63;
        const int wv = tid >> 6;
        const int b  = lb * 4 + wv;
        const int r  = l6 >> 1;

        const float* Lb = leaf + (size_t)b * 1024 + r * 32 + (l6 & 1) * 16;
        const float4 L0 = ((const float4*)Lb)[0];
        const float4 L1 = ((const float4*)Lb)[1];
        const float4 L2 = ((const float4*)Lb)[2];
        const float4 L3 = ((const float4*)Lb)[3];

        const float zl = z[b * 32 + (l6 & 31)];
        const float xr = __shfl(zl, r);

        float4 t0 = make_float4(L0.x * xr, L0.y * xr, L0.z * xr, L0.w * xr);
        float4 t1 = make_float4(L1.x * xr, L1.y * xr, L1.z * xr, L1.w * xr);
        float4 t2 = make_float4(L2.x * xr, L2.y * xr, L2.z * xr, L2.w * xr);
        float4 t3 = make_float4(L3.x * xr, L3.y * xr, L3.z * xr, L3.w * xr);

#pragma unroll
        for (int m = 2; m <= 32; m <<= 1) {
            t0.x += __shfl_xor(t0.x, m); t0.y += __shfl_xor(t0.y, m);
            t0.z += __shfl_xor(t0.z, m); t0.w += __shfl_xor(t0.w, m);
            t1.x += __shfl_xor(t1.x, m); t1.y += __shfl_xor(t1.y, m);
            t1.z += __shfl_xor(t1.z, m); t1.w += __shfl_xor(t1.w, m);
            t2.x += __shfl_xor(t2.x, m); t2.y += __shfl_xor(t2.y, m);
            t2.z += __shfl_xor(t2.z, m); t2.w += __shfl_xor(t2.w, m);
            t3.x += __shfl_xor(t3.x, m); t3.y += __shfl_xor(t3.y, m);
            t3.z += __shfl_xor(t3.z, m); t3.w += __shfl_xor(t3.w, m);
        }

        float yp = L0.x * t0.x + L0.y * t0.y + L0.z * t0.z + L0.w * t0.w
                 + L1.x * t1.x + L1.y * t1.y + L1.z * t1.z + L1.w * t1.w
                 + L2.x * t2.x + L2.y * t2.y + L2.z * t2.z + L2.w * t2.w
                 + L3.x * t3.x + L3.y * t3.y + L3.z * t3.z + L3.w * t3.w;
        yp += __shfl_xor(yp, 1);

        const float w0  = yp + 1e-4f * xr;
        const float out = __shfl(w0, (l6 & 31) * 2);
        if (l6 < 32) w[(size_t)b * 32 + l6] = out;
    }
}

// ---------------------------------------------------------------------------
// K2: tg[(l,h)][r] = sum of partials; one block per (l,h). Zeroes loss+done.
// ---------------------------------------------------------------------------
__global__ __launch_bounds__(256) void k_reduce_t(const float* __restrict__ part,
                                                  float* __restrict__ tg,
                                                  float* __restrict__ loss) {
    const int b = blockIdx.x;
    if (b == 0 && threadIdx.x == 0) { loss[0] = 0.f; ((int*)loss)[1] = 0; }
    const int t = b + 2;
    const int l = 30 - __clz(t);
    const int h = t - (2 << l);
    const int cnt = NSP >> (l + 1);   // spans per half at level l
    const int c0  = h * cnt;
    const int r = threadIdx.x & 15;
    const int g = threadIdx.x >> 4;   // 16 groups

    float s = 0.f;
    for (int c = c0 + g; c < c0 + cnt; c += 16)
        s += part[(l * NSP + c) * 16 + r];

    __shared__ float red[256];
    red[threadIdx.x] = s;
    __syncthreads();
    if (threadIdx.x < 16) {
        float ss = 0.f;
#pragma unroll
        for (int k = 0; k < 16; ++k) ss += red[k * 16 + r];
        tg[((2 << l) - 2 + h) * 16 + r] = ss;
    }
}

// ---------------------------------------------------------------------------
// K3: u-accumulation, LEVEL-PAIR-SEQUENTIAL streaming.
// 1024 blocks x 256 thr, 1 elem/thread: w[i] = w0[i] + sum_l u_l[i].tl_l.
// Per pair: 8 independent float4 loads in flight; streams separated in time.
// ---------------------------------------------------------------------------
__global__ __launch_bounds__(256, 4) void k_uacc(P8 u,
                                                 const float* __restrict__ tg,
                                                 float* __restrict__ w,
                                                 float* __restrict__ y) {
    __shared__ float tl[8][16];
    const int tid  = threadIdx.x;
    const int base = blockIdx.x * SPAN;
    const size_t i = (size_t)(base + tid);

    const float w0 = w[i];            // issue early

    if (tid < 128) {
        const int l = tid >> 4;
        const int r = tid & 15;
        const int h = base >> (17 - l);
        tl[l][r] = tg[(((2 << l) - 2) + (h ^ 1)) * 16 + r];
    }
    __syncthreads();

    float acc = 0.f;
#pragma unroll
    for (int lp = 0; lp < 4; ++lp) {
        const int l = lp * 2;
        const float4* ua = (const float4*)(u.p[l]     + i * RANK);
        const float4* ub = (const float4*)(u.p[l + 1] + i * RANK);
        const float4 a0 = ua[0], a1 = ua[1], a2 = ua[2], a3 = ua[3];
        const float4 b0 = ub[0], b1 = ub[1], b2 = ub[2], b3 = ub[3];

        const float4 s0 = *(const float4*)&tl[l][0];
        const float4 s1 = *(const float4*)&tl[l][4];
        const float4 s2 = *(const float4*)&tl[l][8];
        const float4 s3 = *(const float4*)&tl[l][12];
        acc += a0.x * s0.x + a0.y * s0.y + a0.z * s0.z + a0.w * s0.w
             + a1.x * s1.x + a1.y * s1.y + a1.z * s1.z + a1.w * s1.w
             + a2.x * s2.x + a2.y * s2.y + a2.z * s2.z + a2.w * s2.w
             + a3.x * s3.x + a3.y * s3.y + a3.z * s3.z + a3.w * s3.w;

        const float4 r0 = *(const float4*)&tl[l + 1][0];
        const float4 r1 = *(const float4*)&tl[l + 1][4];
        const float4 r2 = *(const float4*)&tl[l + 1][8];
        const float4 r3 = *(const float4*)&tl[l + 1][12];
        acc += b0.x * r0.x + b0.y * r0.y + b0.z * r0.z + b0.w * r0.w
             + b1.x * r1.x + b1.y * r1.y + b1.z * r1.z + b1.w * r1.w
             + b2.x * r2.x + b2.y * r2.y + b2.z * r2.z + b2.w * r2.w
             + b3.x * r3.x + b3.y * r3.y + b3.z * r3.z + b3.w * r3.w;
    }

    w[i] = w0 + acc;
    if (y) y[i] = 0.f;
}

// ---------------------------------------------------------------------------
// K4: bucket-sort (row, val*w[col]) pairs. 512 blocks x 640 threads.
// ---------------------------------------------------------------------------
__global__ __launch_bounds__(640) void k_bin(const int* __restrict__ idx,
                                             const float* __restrict__ vals,
                                             const float* __restrict__ w,
                                             unsigned long long* __restrict__ gpairs,
                                             int* __restrict__ gdesc) {
    __shared__ unsigned long long pairs[BPB];   // 20 KB
    __shared__ int hist[NBKT];
    __shared__ int scan[NBKT];
    __shared__ int cursor[NBKT];

    const int t  = threadIdx.x;
    const int bl = blockIdx.x;
    const int base = bl * BPB;

    if (t < NBKT) hist[t] = 0;
    __syncthreads();

    int   rows[4];
    float pv[4];
    {
        const int k = base + t * 4;
        const int4   r4 = *(const int4*)(idx + k);
        const int4   c4 = *(const int4*)(idx + NNZ_K + k);
        const float4 v4 = *(const float4*)(vals + k);
        rows[0] = r4.x; pv[0] = v4.x * w[c4.x];
        rows[1] = r4.y; pv[1] = v4.y * w[c4.y];
        rows[2] = r4.z; pv[2] = v4.z * w[c4.z];
        rows[3] = r4.w; pv[3] = v4.w * w[c4.w];
        atomicAdd(&hist[r4.x >> 10], 1);
        atomicAdd(&hist[r4.y >> 10], 1);
        atomicAdd(&hist[r4.z >> 10], 1);
        atomicAdd(&hist[r4.w >> 10], 1);
    }
    __syncthreads();

    int cnt = 0;
    if (t < NBKT) { cnt = hist[t]; scan[t] = cnt; }
    __syncthreads();
    for (int off = 1; off < NBKT; off <<= 1) {
        int add = 0;
        if (t >= off && t < NBKT) add = scan[t - off];
        __syncthreads();
        if (t < NBKT) scan[t] += add;
        __syncthreads();
    }
    if (t < NBKT) {
        const int st = scan[t] - cnt;
        gdesc[t * NB + bl] = st | (cnt << 16);
        cursor[t] = st;
    }
    __syncthreads();

#pragma unroll
    for (int i = 0; i < 4; ++i) {
        const int b   = rows[i] >> 10;
        const int pos = atomicAdd(&cursor[b], 1);
        pairs[pos] = ((unsigned long long)__float_as_uint(pv[i]) << 32) | (unsigned)rows[i];
    }
    __syncthreads();

    const ulonglong2* ps = (const ulonglong2*)pairs;
    ulonglong2*       pd = (ulonglong2*)(gpairs + (size_t)bl * BPB);
#pragma unroll
    for (int i = 0; i < 2; ++i)
        pd[i * 640 + t] = ps[i * 640 + t];
}

// ---------------------------------------------------------------------------
// K5: accumulate rows per bucket + loss; LAST block finalizes out[0]
// (done-counter at ((int*)loss)[1], device-scope atomics).
// ---------------------------------------------------------------------------
__global__ __launch_bounds__(1024) void k_accum(const unsigned long long* __restrict__ gpairs,
                                                const int* __restrict__ gdesc,
                                                const float* __restrict__ z,
                                                float* __restrict__ loss,
                                                float* __restrict__ out) {
    __shared__ float acc[RPB];
    __shared__ float red[16];
    const int t = threadIdx.x;
    const int b = blockIdx.x;
    acc[t] = 0.f;
    __syncthreads();

    {
        const int s  = t >> 1;        // segment, 0..511
        const int h  = t & 1;
        const int d  = gdesc[b * NB + s];
        const int st = d & 0xffff;
        const int c  = d >> 16;
        const unsigned long long* p = gpairs + (size_t)s * BPB + st;
        for (int j = h; j < c; j += 2) {
            const unsigned long long pr = p[j];
            atomicAdd(&acc[(int)(pr & 1023u)], __uint_as_float((unsigned)(pr >> 32)));
        }
    }
    __syncthreads();

    const float d = acc[t] - z[b * RPB + t];
    float s = d * d;
#pragma unroll
    for (int m = 32; m >= 1; m >>= 1) s += __shfl_down(s, m);
    if ((t & 63) == 0) red[t >> 6] = s;
    __syncthreads();
    if (t == 0) {
        float tt = 0.f;
#pragma unroll
        for (int i = 0; i < 16; ++i) tt += red[i];
        atomicAdd(loss, tt);
        __threadfence();
        int* done = (int*)loss + 1;
        if (atomicAdd(done, 1) == NBKT - 1) {
            const float total = atomicAdd(loss, 0.0f);   // coherent read
            out[0] = total * (1.0f / (float)NN);
        }
    }
}

// --------------------------- fallback path (small ws) ----------------------
__global__ __launch_bounds__(256) void k_spmv(const int* __restrict__ idx,
                                              const float* __restrict__ vals,
                                              const float* __restrict__ w,
                                              float* __restrict__ y) {
    const int k = (blockIdx.x * 256 + threadIdx.x) * 4;
    const int4   r4 = *(const int4*)(idx + k);
    const int4   c4 = *(const int4*)(idx + NNZ_K + k);
    const float4 v4 = *(const float4*)(vals + k);
    atomicAdd(&y[r4.x], v4.x * w[c4.x]);
    atomicAdd(&y[r4.y], v4.y * w[c4.y]);
    atomicAdd(&y[r4.z], v4.z * w[c4.z]);
    atomicAdd(&y[r4.w], v4.w * w[c4.w]);
}

__global__ __launch_bounds__(256) void k_loss(const float* __restrict__ y,
                                              const float* __restrict__ z,
                                              float* __restrict__ loss) {
    const int i = blockIdx.x * 256 + threadIdx.x;
    const float4 a = ((const float4*)y)[i];
    const float4 b = ((const float4*)z)[i];
    const float dx = a.x - b.x, dy = a.y - b.y, dz = a.z - b.z, dw = a.w - b.w;
    float s = dx * dx + dy * dy + dz * dz + dw * dw;
#pragma unroll
    for (int m = 32; m >= 1; m >>= 1) s += __shfl_down(s, m);
    __shared__ float r4s[4];
    const int lane = threadIdx.x & 63, wv = threadIdx.x >> 6;
    if (lane == 0) r4s[wv] = s;
    __syncthreads();
    if (threadIdx.x == 0) atomicAdd(loss, r4s[0] + r4s[1] + r4s[2] + r4s[3]);
}

__global__ void k_fin(const float* __restrict__ loss, float* __restrict__ out) {
    out[0] = loss[0] * (1.0f / (float)NN);
}

// ---------------------------------------------------------------------------
extern "C" void kernel_launch(void* const* d_in, const int* in_sizes, int n_in,
                              void* d_out, int out_size, void* d_ws, size_t ws_size,
                              hipStream_t stream) {
    const float* leaf = (const float*)d_in[0];
    P8 u, v;
    for (int l = 0; l < 8; ++l) {
        u.p[l] = (const float*)d_in[1 + 2 * l];
        v.p[l] = (const float*)d_in[2 + 2 * l];
    }
    const int*   Aidx  = (const int*)d_in[17];
    const float* Avals = (const float*)d_in[18];
    const float* z     = (const float*)d_in[19];

    float* ws   = (float*)d_ws;
    // layout (floats):
    float* part  = ws;                     // 8*NSP*16 = 131072
    float* tg    = ws + 131072;            // 8192 -> 139264
    float* loss  = ws + 139264;            // loss[0] + done cnt (pad 64) -> 139328
    float* w     = ws + 139328;            // 262144 -> 401472
    int*   gdesc = (int*)(ws + 401472);    // NBKT*NB = 131072 -> 532544
    unsigned long long* gpairs = (unsigned long long*)(ws + 532544); // NB*BPB*8B
    const size_t need_main = (size_t)(532544 + (size_t)NB * BPB * 2) * 4;

    k_front   <<<NSP + NN / 128, 256, 0, stream>>>(leaf, v, z, part, w);
    k_reduce_t<<<510, 256, 0, stream>>>(part, tg, loss);

    if (ws_size >= need_main) {
        k_uacc <<<NSP, 256, 0, stream>>>(u, tg, w, nullptr);
        k_bin  <<<NB, 640, 0, stream>>>(Aidx, Avals, w, gpairs, gdesc);
        k_accum<<<NBKT, 1024, 0, stream>>>(gpairs, gdesc, z, loss, (float*)d_out);
    } else {
        float* y = ws + 401472 + 262144 <= (float*)((char*)d_ws + ws_size)
                 ? ws + 401472 : ws + 401472;   // y where gdesc would be
        k_uacc <<<NSP, 256, 0, stream>>>(u, tg, w, y);
        k_spmv <<<NNZ_K / 1024, 256, 0, stream>>>(Aidx, Avals, w, y);
        k_loss <<<NN / 1024, 256, 0, stream>>>(y, z, loss);
        k_fin  <<<1, 1, 0, stream>>>(loss, (float*)d_out);
    }
}

// Round 7
// 349.544 us; speedup vs baseline: 4.2315x; 1.0008x over previous
//
#include <hip/hip_runtime.h>

#define NN 262144
#define RANK 16
#define NNZ_K 1310720
#define NB 512           // k_bin blocks
#define BPB 2560         // nnz per k_bin block
#define NBKT 256         // row buckets (1024 rows each)
#define RPB 1024         // rows per bucket
#define SPAN 256         // elems per vt/uacc block
#define NSP 1024         // NN / SPAN

struct P8 { const float* p[8]; };

// XCD-aware swizzle: consecutive blockIdx round-robin across 8 XCDs; remap so
// each XCD works a CONTIGUOUS chunk range (T1). Requires n % 8 == 0 (all uses).
__device__ __forceinline__ int xcd_swz(int bid, int n) {
    return (bid & 7) * (n >> 3) + (bid >> 3);
}

// ---------------------------------------------------------------------------
// K1 "front": fused independent work, XCD-swizzled chunk assignment.
//   bid <  NSP  : v-levels partials (level-sequential within block)
//   bid >= NSP  : leaf matvec w0 = L(L^T x) + 1e-4 x  (wave per 32x32 block)
// ---------------------------------------------------------------------------
__global__ __launch_bounds__(256, 4) void k_front(const float* __restrict__ leaf,
                                                  P8 v,
                                                  const float* __restrict__ z,
                                                  float* __restrict__ part,
                                                  float* __restrict__ w) {
    const int tid = threadIdx.x;

    if (blockIdx.x < NSP) {
        // ---------------- v-levels partials ----------------
        __shared__ float red[8][4][16];
        const int cb   = xcd_swz(blockIdx.x, NSP);
        const int base = cb * SPAN;
        const int q    = tid & 3;
        const int e    = tid >> 2;        // 0..63
        const int lane = tid & 63;
        const int wv   = tid >> 6;        // 0..3

        const float z0 = z[base + e];
        const float z1 = z[base + 64 + e];
        const float z2 = z[base + 128 + e];
        const float z3 = z[base + 192 + e];

#pragma unroll
        for (int l = 0; l < 8; ++l) {
            const float* vp = v.p[l];
            const float4 a0 = *(const float4*)(vp + (size_t)(base + e) * RANK + q * 4);
            const float4 a1 = *(const float4*)(vp + (size_t)(base + 64 + e) * RANK + q * 4);
            const float4 a2 = *(const float4*)(vp + (size_t)(base + 128 + e) * RANK + q * 4);
            const float4 a3 = *(const float4*)(vp + (size_t)(base + 192 + e) * RANK + q * 4);

            float4 acc;
            acc.x = a0.x * z0 + a1.x * z1 + a2.x * z2 + a3.x * z3;
            acc.y = a0.y * z0 + a1.y * z1 + a2.y * z2 + a3.y * z3;
            acc.z = a0.z * z0 + a1.z * z1 + a2.z * z2 + a3.z * z3;
            acc.w = a0.w * z0 + a1.w * z1 + a2.w * z2 + a3.w * z3;

#pragma unroll
            for (int m = 4; m <= 32; m <<= 1) {
                acc.x += __shfl_xor(acc.x, m);
                acc.y += __shfl_xor(acc.y, m);
                acc.z += __shfl_xor(acc.z, m);
                acc.w += __shfl_xor(acc.w, m);
            }
            if (lane < 4) *(float4*)&red[l][wv][lane * 4] = acc;
        }
        __syncthreads();

        if (tid < 128) {
            const int l = tid >> 4;
            const int r = tid & 15;
            const float s = red[l][0][r] + red[l][1][r] + red[l][2][r] + red[l][3][r];
            part[(l * NSP + cb) * 16 + r] = s;
        }
    } else {
        // ---------------- leaf matvec (verbatim-measured math) ----------------
        const int lb = xcd_swz(blockIdx.x - NSP, NN / 128);
        const int l6 = tid & 63;
        const int wv = tid >> 6;
        const int b  = lb * 4 + wv;
        const int r  = l6 >> 1;

        const float* Lb = leaf + (size_t)b * 1024 + r * 32 + (l6 & 1) * 16;
        const float4 L0 = ((const float4*)Lb)[0];
        const float4 L1 = ((const float4*)Lb)[1];
        const float4 L2 = ((const float4*)Lb)[2];
        const float4 L3 = ((const float4*)Lb)[3];

        const float zl = z[b * 32 + (l6 & 31)];
        const float xr = __shfl(zl, r);

        float4 t0 = make_float4(L0.x * xr, L0.y * xr, L0.z * xr, L0.w * xr);
        float4 t1 = make_float4(L1.x * xr, L1.y * xr, L1.z * xr, L1.w * xr);
        float4 t2 = make_float4(L2.x * xr, L2.y * xr, L2.z * xr, L2.w * xr);
        float4 t3 = make_float4(L3.x * xr, L3.y * xr, L3.z * xr, L3.w * xr);

#pragma unroll
        for (int m = 2; m <= 32; m <<= 1) {
            t0.x += __shfl_xor(t0.x, m); t0.y += __shfl_xor(t0.y, m);
            t0.z += __shfl_xor(t0.z, m); t0.w += __shfl_xor(t0.w, m);
            t1.x += __shfl_xor(t1.x, m); t1.y += __shfl_xor(t1.y, m);
            t1.z += __shfl_xor(t1.z, m); t1.w += __shfl_xor(t1.w, m);
            t2.x += __shfl_xor(t2.x, m); t2.y += __shfl_xor(t2.y, m);
            t2.z += __shfl_xor(t2.z, m); t2.w += __shfl_xor(t2.w, m);
            t3.x += __shfl_xor(t3.x, m); t3.y += __shfl_xor(t3.y, m);
            t3.z += __shfl_xor(t3.z, m); t3.w += __shfl_xor(t3.w, m);
        }

        float yp = L0.x * t0.x + L0.y * t0.y + L0.z * t0.z + L0.w * t0.w
                 + L1.x * t1.x + L1.y * t1.y + L1.z * t1.z + L1.w * t1.w
                 + L2.x * t2.x + L2.y * t2.y + L2.z * t2.z + L2.w * t2.w
                 + L3.x * t3.x + L3.y * t3.y + L3.z * t3.z + L3.w * t3.w;
        yp += __shfl_xor(yp, 1);

        const float w0  = yp + 1e-4f * xr;
        const float out = __shfl(w0, (l6 & 31) * 2);
        if (l6 < 32) w[(size_t)b * 32 + l6] = out;
    }
}

// ---------------------------------------------------------------------------
// K2: tg[(l,h)][r] = sum of partials; one block per (l,h). Zeroes loss+done.
// ---------------------------------------------------------------------------
__global__ __launch_bounds__(256) void k_reduce_t(const float* __restrict__ part,
                                                  float* __restrict__ tg,
                                                  float* __restrict__ loss) {
    const int b = blockIdx.x;
    if (b == 0 && threadIdx.x == 0) { loss[0] = 0.f; ((int*)loss)[1] = 0; }
    const int t = b + 2;
    const int l = 30 - __clz(t);
    const int h = t - (2 << l);
    const int cnt = NSP >> (l + 1);   // spans per half at level l
    const int c0  = h * cnt;
    const int r = threadIdx.x & 15;
    const int g = threadIdx.x >> 4;   // 16 groups

    float s = 0.f;
    for (int c = c0 + g; c < c0 + cnt; c += 16)
        s += part[(l * NSP + c) * 16 + r];

    __shared__ float red[256];
    red[threadIdx.x] = s;
    __syncthreads();
    if (threadIdx.x < 16) {
        float ss = 0.f;
#pragma unroll
        for (int k = 0; k < 16; ++k) ss += red[k * 16 + r];
        tg[((2 << l) - 2 + h) * 16 + r] = ss;
    }
}

// ---------------------------------------------------------------------------
// K3: u-accumulation, level-pair-sequential, XCD-swizzled chunk assignment.
// 1024 blocks x 256 thr, 1 elem/thread: w[i] = w0[i] + sum_l u_l[i].tl_l.
// ---------------------------------------------------------------------------
__global__ __launch_bounds__(256, 4) void k_uacc(P8 u,
                                                 const float* __restrict__ tg,
                                                 float* __restrict__ w,
                                                 float* __restrict__ y) {
    __shared__ float tl[8][16];
    const int tid  = threadIdx.x;
    const int base = xcd_swz(blockIdx.x, NSP) * SPAN;
    const size_t i = (size_t)(base + tid);

    const float w0 = w[i];            // issue early

    if (tid < 128) {
        const int l = tid >> 4;
        const int r = tid & 15;
        const int h = base >> (17 - l);
        tl[l][r] = tg[(((2 << l) - 2) + (h ^ 1)) * 16 + r];
    }
    __syncthreads();

    float acc = 0.f;
#pragma unroll
    for (int lp = 0; lp < 4; ++lp) {
        const int l = lp * 2;
        const float4* ua = (const float4*)(u.p[l]     + i * RANK);
        const float4* ub = (const float4*)(u.p[l + 1] + i * RANK);
        const float4 a0 = ua[0], a1 = ua[1], a2 = ua[2], a3 = ua[3];
        const float4 b0 = ub[0], b1 = ub[1], b2 = ub[2], b3 = ub[3];

        const float4 s0 = *(const float4*)&tl[l][0];
        const float4 s1 = *(const float4*)&tl[l][4];
        const float4 s2 = *(const float4*)&tl[l][8];
        const float4 s3 = *(const float4*)&tl[l][12];
        acc += a0.x * s0.x + a0.y * s0.y + a0.z * s0.z + a0.w * s0.w
             + a1.x * s1.x + a1.y * s1.y + a1.z * s1.z + a1.w * s1.w
             + a2.x * s2.x + a2.y * s2.y + a2.z * s2.z + a2.w * s2.w
             + a3.x * s3.x + a3.y * s3.y + a3.z * s3.z + a3.w * s3.w;

        const float4 r0 = *(const float4*)&tl[l + 1][0];
        const float4 r1 = *(const float4*)&tl[l + 1][4];
        const float4 r2 = *(const float4*)&tl[l + 1][8];
        const float4 r3 = *(const float4*)&tl[l + 1][12];
        acc += b0.x * r0.x + b0.y * r0.y + b0.z * r0.z + b0.w * r0.w
             + b1.x * r1.x + b1.y * r1.y + b1.z * r1.z + b1.w * r1.w
             + b2.x * r2.x + b2.y * r2.y + b2.z * r2.z + b2.w * r2.w
             + b3.x * r3.x + b3.y * r3.y + b3.z * r3.z + b3.w * r3.w;
    }

    w[i] = w0 + acc;
    if (y) y[i] = 0.f;
}

// ---------------------------------------------------------------------------
// K4: bucket-sort (row, val*w[col]) pairs. 512 blocks x 640 threads.
// ---------------------------------------------------------------------------
__global__ __launch_bounds__(640) void k_bin(const int* __restrict__ idx,
                                             const float* __restrict__ vals,
                                             const float* __restrict__ w,
                                             unsigned long long* __restrict__ gpairs,
                                             int* __restrict__ gdesc) {
    __shared__ unsigned long long pairs[BPB];   // 20 KB
    __shared__ int hist[NBKT];
    __shared__ int scan[NBKT];
    __shared__ int cursor[NBKT];

    const int t  = threadIdx.x;
    const int bl = blockIdx.x;
    const int base = bl * BPB;

    if (t < NBKT) hist[t] = 0;
    __syncthreads();

    int   rows[4];
    float pv[4];
    {
        const int k = base + t * 4;
        const int4   r4 = *(const int4*)(idx + k);
        const int4   c4 = *(const int4*)(idx + NNZ_K + k);
        const float4 v4 = *(const float4*)(vals + k);
        rows[0] = r4.x; pv[0] = v4.x * w[c4.x];
        rows[1] = r4.y; pv[1] = v4.y * w[c4.y];
        rows[2] = r4.z; pv[2] = v4.z * w[c4.z];
        rows[3] = r4.w; pv[3] = v4.w * w[c4.w];
        atomicAdd(&hist[r4.x >> 10], 1);
        atomicAdd(&hist[r4.y >> 10], 1);
        atomicAdd(&hist[r4.z >> 10], 1);
        atomicAdd(&hist[r4.w >> 10], 1);
    }
    __syncthreads();

    int cnt = 0;
    if (t < NBKT) { cnt = hist[t]; scan[t] = cnt; }
    __syncthreads();
    for (int off = 1; off < NBKT; off <<= 1) {
        int add = 0;
        if (t >= off && t < NBKT) add = scan[t - off];
        __syncthreads();
        if (t < NBKT) scan[t] += add;
        __syncthreads();
    }
    if (t < NBKT) {
        const int st = scan[t] - cnt;
        gdesc[t * NB + bl] = st | (cnt << 16);
        cursor[t] = st;
    }
    __syncthreads();

#pragma unroll
    for (int i = 0; i < 4; ++i) {
        const int b   = rows[i] >> 10;
        const int pos = atomicAdd(&cursor[b], 1);
        pairs[pos] = ((unsigned long long)__float_as_uint(pv[i]) << 32) | (unsigned)rows[i];
    }
    __syncthreads();

    const ulonglong2* ps = (const ulonglong2*)pairs;
    ulonglong2*       pd = (ulonglong2*)(gpairs + (size_t)bl * BPB);
#pragma unroll
    for (int i = 0; i < 2; ++i)
        pd[i * 640 + t] = ps[i * 640 + t];
}

// ---------------------------------------------------------------------------
// K5: accumulate rows per bucket + loss; LAST block finalizes out[0]
// (done-counter at ((int*)loss)[1], device-scope atomics).
// ---------------------------------------------------------------------------
__global__ __launch_bounds__(1024) void k_accum(const unsigned long long* __restrict__ gpairs,
                                                const int* __restrict__ gdesc,
                                                const float* __restrict__ z,
                                                float* __restrict__ loss,
                                                float* __restrict__ out) {
    __shared__ float acc[RPB];
    __shared__ float red[16];
    const int t = threadIdx.x;
    const int b = blockIdx.x;
    acc[t] = 0.f;
    __syncthreads();

    {
        const int s  = t >> 1;        // segment, 0..511
        const int h  = t & 1;
        const int d  = gdesc[b * NB + s];
        const int st = d & 0xffff;
        const int c  = d >> 16;
        const unsigned long long* p = gpairs + (size_t)s * BPB + st;
        for (int j = h; j < c; j += 2) {
            const unsigned long long pr = p[j];
            atomicAdd(&acc[(int)(pr & 1023u)], __uint_as_float((unsigned)(pr >> 32)));
        }
    }
    __syncthreads();

    const float d = acc[t] - z[b * RPB + t];
    float s = d * d;
#pragma unroll
    for (int m = 32; m >= 1; m >>= 1) s += __shfl_down(s, m);
    if ((t & 63) == 0) red[t >> 6] = s;
    __syncthreads();
    if (t == 0) {
        float tt = 0.f;
#pragma unroll
        for (int i = 0; i < 16; ++i) tt += red[i];
        atomicAdd(loss, tt);
        __threadfence();
        int* done = (int*)loss + 1;
        if (atomicAdd(done, 1) == NBKT - 1) {
            const float total = atomicAdd(loss, 0.0f);   // coherent read
            out[0] = total * (1.0f / (float)NN);
        }
    }
}

// --------------------------- fallback path (small ws) ----------------------
__global__ __launch_bounds__(256) void k_spmv(const int* __restrict__ idx,
                                              const float* __restrict__ vals,
                                              const float* __restrict__ w,
                                              float* __restrict__ y) {
    const int k = (blockIdx.x * 256 + threadIdx.x) * 4;
    const int4   r4 = *(const int4*)(idx + k);
    const int4   c4 = *(const int4*)(idx + NNZ_K + k);
    const float4 v4 = *(const float4*)(vals + k);
    atomicAdd(&y[r4.x], v4.x * w[c4.x]);
    atomicAdd(&y[r4.y], v4.y * w[c4.y]);
    atomicAdd(&y[r4.z], v4.z * w[c4.z]);
    atomicAdd(&y[r4.w], v4.w * w[c4.w]);
}

__global__ __launch_bounds__(256) void k_loss(const float* __restrict__ y,
                                              const float* __restrict__ z,
                                              float* __restrict__ loss) {
    const int i = blockIdx.x * 256 + threadIdx.x;
    const float4 a = ((const float4*)y)[i];
    const float4 b = ((const float4*)z)[i];
    const float dx = a.x - b.x, dy = a.y - b.y, dz = a.z - b.z, dw = a.w - b.w;
    float s = dx * dx + dy * dy + dz * dz + dw * dw;
#pragma unroll
    for (int m = 32; m >= 1; m >>= 1) s += __shfl_down(s, m);
    __shared__ float r4s[4];
    const int lane = threadIdx.x & 63, wv = threadIdx.x >> 6;
    if (lane == 0) r4s[wv] = s;
    __syncthreads();
    if (threadIdx.x == 0) atomicAdd(loss, r4s[0] + r4s[1] + r4s[2] + r4s[3]);
}

__global__ void k_fin(const float* __restrict__ loss, float* __restrict__ out) {
    out[0] = loss[0] * (1.0f / (float)NN);
}

// ---------------------------------------------------------------------------
extern "C" void kernel_launch(void* const* d_in, const int* in_sizes, int n_in,
                              void* d_out, int out_size, void* d_ws, size_t ws_size,
                              hipStream_t stream) {
    const float* leaf = (const float*)d_in[0];
    P8 u, v;
    for (int l = 0; l < 8; ++l) {
        u.p[l] = (const float*)d_in[1 + 2 * l];
        v.p[l] = (const float*)d_in[2 + 2 * l];
    }
    const int*   Aidx  = (const int*)d_in[17];
    const float* Avals = (const float*)d_in[18];
    const float* z     = (const float*)d_in[19];

    float* ws   = (float*)d_ws;
    // layout (floats):
    float* part  = ws;                     // 8*NSP*16 = 131072
    float* tg    = ws + 131072;            // 8192 -> 139264
    float* loss  = ws + 139264;            // loss[0] + done cnt (pad 64) -> 139328
    float* w     = ws + 139328;            // 262144 -> 401472
    int*   gdesc = (int*)(ws + 401472);    // NBKT*NB = 131072 -> 532544
    unsigned long long* gpairs = (unsigned long long*)(ws + 532544); // NB*BPB*8B
    const size_t need_main = (size_t)(532544 + (size_t)NB * BPB * 2) * 4;

    k_front   <<<NSP + NN / 128, 256, 0, stream>>>(leaf, v, z, part, w);
    k_reduce_t<<<510, 256, 0, stream>>>(part, tg, loss);

    if (ws_size >= need_main) {
        k_uacc <<<NSP, 256, 0, stream>>>(u, tg, w, nullptr);
        k_bin  <<<NB, 640, 0, stream>>>(Aidx, Avals, w, gpairs, gdesc);
        k_accum<<<NBKT, 1024, 0, stream>>>(gpairs, gdesc, z, loss, (float*)d_out);
    } else {
        float* y = ws + 401472;            // fallback: y where gdesc would be
        k_uacc <<<NSP, 256, 0, stream>>>(u, tg, w, y);
        k_spmv <<<NNZ_K / 1024, 256, 0, stream>>>(Aidx, Avals, w, y);
        k_loss <<<NN / 1024, 256, 0, stream>>>(y, z, loss);
        k_fin  <<<1, 1, 0, stream>>>(loss, (float*)d_out);
    }
}